// Round 3
// baseline (281.818 us; speedup 1.0000x reference)
//
#include <hip/hip_runtime.h>

#define IN_F 128
#define OUT_F 128

typedef __attribute__((ext_vector_type(8))) short short8;   // 8 bf16 = 4 VGPRs
typedef __attribute__((ext_vector_type(4))) float floatx4;  // MFMA C/D

// fp32 -> bf16 (RNE) as raw short
__device__ __forceinline__ short f2bf(float f) {
  union { float f; unsigned u; } v; v.f = f;
  unsigned u = v.u;
  unsigned r = (u + 0x7fffu + ((u >> 16) & 1u)) >> 16;
  return (short)r;
}

// ---------------------------------------------------------------------------
// Prep: wt[n][k] = bf16(W[k][n])  (transposed so B-frag loads are contiguous)
// ---------------------------------------------------------------------------
__global__ __launch_bounds__(256) void prep_wt(const float* __restrict__ w,
                                               short* __restrict__ wt) {
  int i = blockIdx.x * 256 + threadIdx.x;   // i = n*128 + k
  int n = i >> 7, k = i & 127;
  wt[i] = f2bf(w[k * 128 + n]);
}

// ---------------------------------------------------------------------------
// GEMM: support(bf16) = X(fp32->bf16) @ W via mfma_f32_16x16x32_bf16.
// Block = 256 thr = 4 waves; block tile M=64 (wave w -> rows +16w), N=128.
// A-frag: A[m=lane&15][k=(lane>>4)*8+j]; B-frag: B[k][n=lane&15] same k-map.
// C/D: col=lane&15, row=(lane>>4)*4+reg.
// ---------------------------------------------------------------------------
__global__ __launch_bounds__(256) void gemm_mfma(const float* __restrict__ x,
                                                 const short* __restrict__ wt,
                                                 unsigned short* __restrict__ sup,
                                                 int n) {
  const int w    = threadIdx.x >> 6;
  const int lane = threadIdx.x & 63;
  const int m    = lane & 15;
  const int q    = lane >> 4;
  const int row  = blockIdx.x * 64 + w * 16 + m;

  floatx4 acc[8];
#pragma unroll
  for (int t = 0; t < 8; ++t) acc[t] = (floatx4)(0.f);

#pragma unroll
  for (int kk = 0; kk < 4; ++kk) {
    short8 a;
    if (row < n) {
      const float4* px = (const float4*)(x + (size_t)row * IN_F + kk * 32 + q * 8);
      float4 lo = px[0], hi = px[1];
      a[0] = f2bf(lo.x); a[1] = f2bf(lo.y); a[2] = f2bf(lo.z); a[3] = f2bf(lo.w);
      a[4] = f2bf(hi.x); a[5] = f2bf(hi.y); a[6] = f2bf(hi.z); a[7] = f2bf(hi.w);
    } else {
      a = (short8)(0);
    }
#pragma unroll
    for (int t = 0; t < 8; ++t) {
      short8 b = *(const short8*)(wt + (size_t)(16 * t + m) * 128 + kk * 32 + q * 8);
      acc[t] = __builtin_amdgcn_mfma_f32_16x16x32_bf16(a, b, acc[t], 0, 0, 0);
    }
  }

#pragma unroll
  for (int r = 0; r < 4; ++r) {
    int row_out = blockIdx.x * 64 + w * 16 + q * 4 + r;
    if (row_out < n) {
#pragma unroll
      for (int t = 0; t < 8; ++t) {
        sup[(size_t)row_out * OUT_F + 16 * t + m] = (unsigned short)f2bf(acc[t][r]);
      }
    }
  }
}

// ---------------------------------------------------------------------------
// CSR build: zero -> histogram -> 3-kernel exclusive scan -> bucket scatter
// ---------------------------------------------------------------------------
__global__ __launch_bounds__(256) void zero_counts(int* __restrict__ counts, int L) {
  int i = blockIdx.x * 256 + threadIdx.x;
  if (i < L) counts[i] = 0;
}

__global__ __launch_bounds__(256) void hist_rows(const int* __restrict__ erow,
                                                 int* __restrict__ counts, int n_edges) {
  int e = blockIdx.x * 256 + threadIdx.x;
  if (e < n_edges) atomicAdd(&counts[erow[e]], 1);
}

__device__ __forceinline__ int block_excl_scan_256(int v, int* sdata) {
  int t = threadIdx.x;
  sdata[t] = v;
  __syncthreads();
#pragma unroll
  for (int d = 1; d < 256; d <<= 1) {
    int add = (t >= d) ? sdata[t - d] : 0;
    __syncthreads();
    sdata[t] += add;
    __syncthreads();
  }
  return sdata[t] - v;
}

__global__ __launch_bounds__(256) void scan_chunks(const int* __restrict__ counts,
                                                   int* __restrict__ offsets,
                                                   int* __restrict__ partials, int L) {
  __shared__ int sdata[256];
  int t = threadIdx.x;
  int base = blockIdx.x * 1024 + t * 4;
  int a[4];
#pragma unroll
  for (int i = 0; i < 4; ++i) { int idx = base + i; a[i] = (idx < L) ? counts[idx] : 0; }
  int local = a[0] + a[1] + a[2] + a[3];
  int pre = block_excl_scan_256(local, sdata);
  int run = pre;
#pragma unroll
  for (int i = 0; i < 4; ++i) { int idx = base + i; if (idx < L) offsets[idx] = run; run += a[i]; }
  if (t == 255) partials[blockIdx.x] = pre + local;
}

__global__ __launch_bounds__(256) void scan_partials(int* __restrict__ partials, int nChunks) {
  __shared__ int sdata[256];
  int t = threadIdx.x;
  int v = (t < nChunks) ? partials[t] : 0;
  int pre = block_excl_scan_256(v, sdata);
  if (t < nChunks) partials[t] = pre;
}

__global__ __launch_bounds__(256) void add_partials(int* __restrict__ offsets,
                                                    const int* __restrict__ partials,
                                                    int* __restrict__ cursor,
                                                    int L, int n_nodes) {
  int i = blockIdx.x * 256 + threadIdx.x;
  if (i < L) {
    int v = offsets[i] + partials[i >> 10];
    offsets[i] = v;
    if (i < n_nodes) cursor[i] = v;
  }
}

__global__ __launch_bounds__(256) void scatter_edges(const int* __restrict__ erow,
                                                     const int* __restrict__ ecol,
                                                     const float* __restrict__ eval_,
                                                     int* __restrict__ cursor,
                                                     int2* __restrict__ sedge, int n_edges) {
  int e = blockIdx.x * 256 + threadIdx.x;
  if (e < n_edges) {
    int r = erow[e];
    int pos = atomicAdd(&cursor[r], 1);
    sedge[pos] = make_int2(ecol[e], __float_as_int(eval_[e]));
  }
}

// ---------------------------------------------------------------------------
// Gather: one wave per destination row. support row = 256 B bf16 -> one dword
// per lane (bf16x2). fp32 accumulate, bias folded, single coalesced write.
// Prefetch next edge record to break the sedge -> support dependent chain.
// ---------------------------------------------------------------------------
__global__ __launch_bounds__(256) void gather_csr(const int* __restrict__ offsets,
                                                  const int2* __restrict__ sedge,
                                                  const unsigned* __restrict__ sup,
                                                  const float* __restrict__ bias,
                                                  float* __restrict__ out, int n_nodes) {
  int row  = (int)((blockIdx.x * 256 + threadIdx.x) >> 6);
  int lane = threadIdx.x & 63;
  if (row >= n_nodes) return;
  int start = __builtin_amdgcn_readfirstlane(offsets[row]);
  int end   = __builtin_amdgcn_readfirstlane(offsets[row + 1]);
  float2 acc = make_float2(0.f, 0.f);
  int2 cv = (start < end) ? sedge[start] : make_int2(0, 0);
  for (int j = start; j < end; ++j) {
    int2 nx = (j + 1 < end) ? sedge[j + 1] : cv;
    unsigned s = sup[(size_t)cv.x * 64 + lane];
    float v = __int_as_float(cv.y);
    acc.x = fmaf(v, __uint_as_float(s << 16), acc.x);
    acc.y = fmaf(v, __uint_as_float(s & 0xffff0000u), acc.y);
    cv = nx;
  }
  float2 b = ((const float2*)bias)[lane];
  ((float2*)out)[(size_t)row * 64 + lane] = make_float2(acc.x + b.x, acc.y + b.y);
}

extern "C" void kernel_launch(void* const* d_in, const int* in_sizes, int n_in,
                              void* d_out, int out_size, void* d_ws, size_t ws_size,
                              hipStream_t stream) {
  const float* x     = (const float*)d_in[0];
  const int*   erow  = (const int*)d_in[1];
  const int*   ecol  = (const int*)d_in[2];
  const float* eval_ = (const float*)d_in[3];
  const float* w     = (const float*)d_in[4];
  const float* bias  = (const float*)d_in[5];
  float* out = (float*)d_out;

  const int n_nodes = in_sizes[0] / IN_F;
  const int n_edges = in_sizes[1];
  const int L = n_nodes + 1;

  char* ws = (char*)d_ws;
  size_t off = 0;
  auto carve = [&](size_t bytes) { void* p = ws + off; off = (off + bytes + 255) & ~(size_t)255; return p; };
  unsigned short* sup = (unsigned short*)carve((size_t)n_nodes * OUT_F * sizeof(unsigned short)); // 12.8 MB
  short* wt           = (short*)carve((size_t)IN_F * OUT_F * sizeof(short));                      // 32 KB
  int*   counts   = (int*)  carve((size_t)L * sizeof(int));
  int*   offsets  = (int*)  carve((size_t)L * sizeof(int));
  int*   cursor   = (int*)  carve((size_t)n_nodes * sizeof(int));
  int*   partials = (int*)  carve(256 * sizeof(int));
  int2*  sedge    = (int2*) carve((size_t)n_edges * sizeof(int2));                                // 6.4 MB

  const int nChunks = (L + 1023) / 1024;

  prep_wt<<<(IN_F * OUT_F) / 256, 256, 0, stream>>>(w, wt);
  gemm_mfma<<<(n_nodes + 63) / 64, 256, 0, stream>>>(x, wt, sup, n_nodes);

  zero_counts<<<(L + 255) / 256, 256, 0, stream>>>(counts, L);
  hist_rows<<<(n_edges + 255) / 256, 256, 0, stream>>>(erow, counts, n_edges);
  scan_chunks<<<nChunks, 256, 0, stream>>>(counts, offsets, partials, L);
  scan_partials<<<1, 256, 0, stream>>>(partials, nChunks);
  add_partials<<<(L + 255) / 256, 256, 0, stream>>>(offsets, partials, cursor, L, n_nodes);
  scatter_edges<<<(n_edges + 255) / 256, 256, 0, stream>>>(erow, ecol, eval_, cursor, sedge, n_edges);

  gather_csr<<<(n_nodes + 3) / 4, 256, 0, stream>>>(offsets, sedge, (const unsigned*)sup, bias, out, n_nodes);
}

// Round 4
// 230.052 us; speedup vs baseline: 1.2250x; 1.2250x over previous
//
#include <hip/hip_runtime.h>

#define IN_F 128
#define OUT_F 128

typedef __attribute__((ext_vector_type(8))) short short8;   // 8 bf16 = 4 VGPRs
typedef __attribute__((ext_vector_type(4))) float floatx4;  // MFMA C/D

// fp32 -> bf16 (RNE) as raw short
__device__ __forceinline__ short f2bf(float f) {
  union { float f; unsigned u; } v; v.f = f;
  unsigned u = v.u;
  unsigned r = (u + 0x7fffu + ((u >> 16) & 1u)) >> 16;
  return (short)r;
}
__device__ __forceinline__ float bflo(unsigned u) { return __uint_as_float(u << 16); }
__device__ __forceinline__ float bfhi(unsigned u) { return __uint_as_float(u & 0xffff0000u); }

// ---------------------------------------------------------------------------
// Prep: wt[n][k] = bf16(W[k][n])  (transposed so B-frag loads are contiguous)
// ---------------------------------------------------------------------------
__global__ __launch_bounds__(256) void prep_wt(const float* __restrict__ w,
                                               short* __restrict__ wt) {
  int i = blockIdx.x * 256 + threadIdx.x;   // i = n*128 + k
  int n = i >> 7, k = i & 127;
  wt[i] = f2bf(w[k * 128 + n]);
}

// ---------------------------------------------------------------------------
// GEMM: support(bf16) = X(fp32->bf16) @ W via mfma_f32_16x16x32_bf16.
// ---------------------------------------------------------------------------
__global__ __launch_bounds__(256) void gemm_mfma(const float* __restrict__ x,
                                                 const short* __restrict__ wt,
                                                 unsigned short* __restrict__ sup,
                                                 int n) {
  const int w    = threadIdx.x >> 6;
  const int lane = threadIdx.x & 63;
  const int m    = lane & 15;
  const int q    = lane >> 4;
  const int row  = blockIdx.x * 64 + w * 16 + m;

  floatx4 acc[8];
#pragma unroll
  for (int t = 0; t < 8; ++t) acc[t] = (floatx4)(0.f);

#pragma unroll
  for (int kk = 0; kk < 4; ++kk) {
    short8 a;
    if (row < n) {
      const float4* px = (const float4*)(x + (size_t)row * IN_F + kk * 32 + q * 8);
      float4 lo = px[0], hi = px[1];
      a[0] = f2bf(lo.x); a[1] = f2bf(lo.y); a[2] = f2bf(lo.z); a[3] = f2bf(lo.w);
      a[4] = f2bf(hi.x); a[5] = f2bf(hi.y); a[6] = f2bf(hi.z); a[7] = f2bf(hi.w);
    } else {
      a = (short8)(0);
    }
#pragma unroll
    for (int t = 0; t < 8; ++t) {
      short8 b = *(const short8*)(wt + (size_t)(16 * t + m) * 128 + kk * 32 + q * 8);
      acc[t] = __builtin_amdgcn_mfma_f32_16x16x32_bf16(a, b, acc[t], 0, 0, 0);
    }
  }

#pragma unroll
  for (int r = 0; r < 4; ++r) {
    int row_out = blockIdx.x * 64 + w * 16 + q * 4 + r;
    if (row_out < n) {
#pragma unroll
      for (int t = 0; t < 8; ++t) {
        sup[(size_t)row_out * OUT_F + 16 * t + m] = (unsigned short)f2bf(acc[t][r]);
      }
    }
  }
}

// ---------------------------------------------------------------------------
// CSR build: zero -> histogram -> 3-kernel exclusive scan -> bucket scatter
// ---------------------------------------------------------------------------
__global__ __launch_bounds__(256) void zero_counts(int* __restrict__ counts, int L) {
  int i = blockIdx.x * 256 + threadIdx.x;
  if (i < L) counts[i] = 0;
}

__global__ __launch_bounds__(256) void hist_rows(const int* __restrict__ erow,
                                                 int* __restrict__ counts, int n_edges) {
  int e = blockIdx.x * 256 + threadIdx.x;
  if (e < n_edges) atomicAdd(&counts[erow[e]], 1);
}

__device__ __forceinline__ int block_excl_scan_256(int v, int* sdata) {
  int t = threadIdx.x;
  sdata[t] = v;
  __syncthreads();
#pragma unroll
  for (int d = 1; d < 256; d <<= 1) {
    int add = (t >= d) ? sdata[t - d] : 0;
    __syncthreads();
    sdata[t] += add;
    __syncthreads();
  }
  return sdata[t] - v;
}

__global__ __launch_bounds__(256) void scan_chunks(const int* __restrict__ counts,
                                                   int* __restrict__ offsets,
                                                   int* __restrict__ partials, int L) {
  __shared__ int sdata[256];
  int t = threadIdx.x;
  int base = blockIdx.x * 1024 + t * 4;
  int a[4];
#pragma unroll
  for (int i = 0; i < 4; ++i) { int idx = base + i; a[i] = (idx < L) ? counts[idx] : 0; }
  int local = a[0] + a[1] + a[2] + a[3];
  int pre = block_excl_scan_256(local, sdata);
  int run = pre;
#pragma unroll
  for (int i = 0; i < 4; ++i) { int idx = base + i; if (idx < L) offsets[idx] = run; run += a[i]; }
  if (t == 255) partials[blockIdx.x] = pre + local;
}

__global__ __launch_bounds__(256) void scan_partials(int* __restrict__ partials, int nChunks) {
  __shared__ int sdata[256];
  int t = threadIdx.x;
  int v = (t < nChunks) ? partials[t] : 0;
  int pre = block_excl_scan_256(v, sdata);
  if (t < nChunks) partials[t] = pre;
}

__global__ __launch_bounds__(256) void add_partials(int* __restrict__ offsets,
                                                    const int* __restrict__ partials,
                                                    int* __restrict__ cursor,
                                                    int L, int n_nodes) {
  int i = blockIdx.x * 256 + threadIdx.x;
  if (i < L) {
    int v = offsets[i] + partials[i >> 10];
    offsets[i] = v;
    if (i < n_nodes) cursor[i] = v;
  }
}

__global__ __launch_bounds__(256) void scatter_edges(const int* __restrict__ erow,
                                                     const int* __restrict__ ecol,
                                                     const float* __restrict__ eval_,
                                                     int* __restrict__ cursor,
                                                     int2* __restrict__ sedge, int n_edges) {
  int e = blockIdx.x * 256 + threadIdx.x;
  if (e < n_edges) {
    int r = erow[e];
    int pos = atomicAdd(&cursor[r], 1);
    sedge[pos] = make_int2(ecol[e], __float_as_int(eval_[e]));
  }
}

// ---------------------------------------------------------------------------
// Gather: 4 rows per wave (16 lanes each), uint4 (8 bf16 features) per lane.
// One load instruction moves 1 KB (4 independent rows) vs 256 B before -> 4x
// memory-level parallelism. 2-deep software pipeline on (edge rec, sup vec).
// ---------------------------------------------------------------------------
__global__ __launch_bounds__(256) void gather_csr(const int* __restrict__ offsets,
                                                  const int2* __restrict__ sedge,
                                                  const uint4* __restrict__ supv,
                                                  const float* __restrict__ bias,
                                                  float* __restrict__ out,
                                                  int n_nodes, int n_edges) {
  const int wave_id = (int)((blockIdx.x * 256 + threadIdx.x) >> 6);
  const int lane = threadIdx.x & 63;
  const int g = lane >> 4;       // row within wave's group of 4
  const int s = lane & 15;       // feature sub-segment (8 features)
  const int row = wave_id * 4 + g;

  int start = 0, end = 0;
  if (row < n_nodes) { start = offsets[row]; end = offsets[row + 1]; }
  const int cnt = end - start;
  // wave-level max trip count over the 4 groups
  int mx = max(cnt, __shfl_xor(cnt, 16));
  mx = max(mx, __shfl_xor(mx, 32));

  float a0 = 0.f, a1 = 0.f, a2 = 0.f, a3 = 0.f, a4 = 0.f, a5 = 0.f, a6 = 0.f, a7 = 0.f;

  const int eMax = n_edges - 1;
  const int cm1 = max(cnt - 1, 0);
  // prime 2-stage pipeline (indices clamped; exhausted rows contribute v=0)
  int2 rec0 = sedge[min(start, eMax)];                 // edge j
  uint4 sv  = supv[(size_t)rec0.x * 16 + s];           // sup vec for edge j
  int2 rec1 = sedge[min(start + min(1, cm1), eMax)];   // edge j+1

  for (int j = 0; j < mx; ++j) {
    float v = (j < cnt) ? __int_as_float(rec0.y) : 0.f;
    uint4 svn = supv[(size_t)rec1.x * 16 + s];         // issue load j+1
    int2 rec2 = sedge[min(start + min(j + 2, cm1), eMax)];  // prefetch rec j+2
    a0 = fmaf(v, bflo(sv.x), a0);
    a1 = fmaf(v, bfhi(sv.x), a1);
    a2 = fmaf(v, bflo(sv.y), a2);
    a3 = fmaf(v, bfhi(sv.y), a3);
    a4 = fmaf(v, bflo(sv.z), a4);
    a5 = fmaf(v, bfhi(sv.z), a5);
    a6 = fmaf(v, bflo(sv.w), a6);
    a7 = fmaf(v, bfhi(sv.w), a7);
    sv = svn; rec0 = rec1; rec1 = rec2;
  }

  if (row < n_nodes) {
    const float4* bp = (const float4*)bias + s * 2;
    float4 b0 = bp[0], b1 = bp[1];
    float4* op = (float4*)(out + (size_t)row * OUT_F + s * 8);
    op[0] = make_float4(a0 + b0.x, a1 + b0.y, a2 + b0.z, a3 + b0.w);
    op[1] = make_float4(a4 + b1.x, a5 + b1.y, a6 + b1.z, a7 + b1.w);
  }
}

extern "C" void kernel_launch(void* const* d_in, const int* in_sizes, int n_in,
                              void* d_out, int out_size, void* d_ws, size_t ws_size,
                              hipStream_t stream) {
  const float* x     = (const float*)d_in[0];
  const int*   erow  = (const int*)d_in[1];
  const int*   ecol  = (const int*)d_in[2];
  const float* eval_ = (const float*)d_in[3];
  const float* w     = (const float*)d_in[4];
  const float* bias  = (const float*)d_in[5];
  float* out = (float*)d_out;

  const int n_nodes = in_sizes[0] / IN_F;
  const int n_edges = in_sizes[1];
  const int L = n_nodes + 1;

  char* ws = (char*)d_ws;
  size_t off = 0;
  auto carve = [&](size_t bytes) { void* p = ws + off; off = (off + bytes + 255) & ~(size_t)255; return p; };
  unsigned short* sup = (unsigned short*)carve((size_t)n_nodes * OUT_F * sizeof(unsigned short)); // 12.8 MB
  short* wt           = (short*)carve((size_t)IN_F * OUT_F * sizeof(short));                      // 32 KB
  int*   counts   = (int*)  carve((size_t)L * sizeof(int));
  int*   offsets  = (int*)  carve((size_t)L * sizeof(int));
  int*   cursor   = (int*)  carve((size_t)n_nodes * sizeof(int));
  int*   partials = (int*)  carve(256 * sizeof(int));
  int2*  sedge    = (int2*) carve((size_t)n_edges * sizeof(int2));                                // 6.4 MB

  const int nChunks = (L + 1023) / 1024;

  prep_wt<<<(IN_F * OUT_F) / 256, 256, 0, stream>>>(w, wt);
  gemm_mfma<<<(n_nodes + 63) / 64, 256, 0, stream>>>(x, wt, sup, n_nodes);

  zero_counts<<<(L + 255) / 256, 256, 0, stream>>>(counts, L);
  hist_rows<<<(n_edges + 255) / 256, 256, 0, stream>>>(erow, counts, n_edges);
  scan_chunks<<<nChunks, 256, 0, stream>>>(counts, offsets, partials, L);
  scan_partials<<<1, 256, 0, stream>>>(partials, nChunks);
  add_partials<<<(L + 255) / 256, 256, 0, stream>>>(offsets, partials, cursor, L, n_nodes);
  scatter_edges<<<(n_edges + 255) / 256, 256, 0, stream>>>(erow, ecol, eval_, cursor, sedge, n_edges);

  // 16 rows per block (4 waves x 4 rows)
  gather_csr<<<(n_nodes + 15) / 16, 256, 0, stream>>>(offsets, sedge, (const uint4*)sup,
                                                      bias, out, n_nodes, n_edges);
}